// Round 2
// baseline (55.617 us; speedup 1.0000x reference)
//
#include <hip/hip_runtime.h>
#include <stdint.h>

#define B_ 4
#define C_ 1
#define D_ 128
#define HW_ 65536          // 256*256
#define K_ 4
#define NBC (B_*C_)
#define GPB (HW_/4)        // float4 groups per depth slice per (b,c) = 16384
#define SCALE_ 100000.0f
#define EPS_ 1e-15f

typedef unsigned long long u64;

__global__ __launch_bounds__(64) void init_mm_kernel(unsigned int* mm) {
    int t = threadIdx.x;
    if (t < NBC) {
        mm[2*t]   = 0x7F800000u;  // +inf  (min slot)
        mm[2*t+1] = 0u;           // 0.0f  (max slot; all values >= 0)
    }
}

__device__ __forceinline__ u64 umax64(u64 a, u64 b) { return a > b ? a : b; }

__device__ __forceinline__ void cswap_u64(u64& hi, u64& lo) {
    u64 a = hi, b = lo;
    bool sw = b > a;
    hi = sw ? b : a;
    lo = sw ? a : b;
}

// 4-way depth split: lane quarter (gt&3) scans 32 depth slices of one float4
// column-group; merge across the quad via 2 bitonic shfl_xor stages on u64 keys.
__global__ __launch_bounds__(256, 4) void topk_kernel(const float* __restrict__ x,
                                                      float* __restrict__ out,
                                                      unsigned int* __restrict__ mm) {
    const int gt      = blockIdx.x * 256 + threadIdx.x;
    const int quarter = gt & 3;
    const int gq      = gt >> 2;            // column-group id over all (b,c)
    const int bc      = gq >> 14;           // / GPB
    const int grp     = gq & (GPB - 1);

    const float4* __restrict__ src = (const float4*)x
        + (size_t)bc * (D_ * GPB) + (size_t)(quarter * (D_/4)) * GPB + grp;

    // per-column top-4, sorted desc; strict > keeps earliest depth on ties
    float lv[4][K_];
    int   li[4][K_];
    #pragma unroll
    for (int j = 0; j < 4; ++j)
        #pragma unroll
        for (int k = 0; k < K_; ++k) { lv[j][k] = -1.0f; li[j][k] = 0; }

    float mn = __int_as_float(0x7F800000);  // +inf
    const int dbase = quarter * (D_/4);

    #pragma unroll 8
    for (int dd = 0; dd < D_/4; ++dd) {
        const float4 q = src[(size_t)dd * GPB];
        const int d = dbase + dd;
        float vx[4] = { fmaxf(q.x, 0.0f), fmaxf(q.y, 0.0f),
                        fmaxf(q.z, 0.0f), fmaxf(q.w, 0.0f) };
        #pragma unroll
        for (int j = 0; j < 4; ++j) {
            const float v = vx[j];
            mn = fminf(mn, v);
            const bool ins = v > lv[j][3];
            lv[j][3] = ins ? v : lv[j][3];
            li[j][3] = ins ? d : li[j][3];
            #pragma unroll
            for (int k = 3; k > 0; --k) {
                const bool sw = lv[j][k] > lv[j][k-1];
                const float tv = sw ? lv[j][k-1] : lv[j][k];
                const int   ti = sw ? li[j][k-1] : li[j][k];
                lv[j][k-1] = sw ? lv[j][k] : lv[j][k-1];
                li[j][k-1] = sw ? li[j][k] : li[j][k-1];
                lv[j][k] = tv;  li[j][k] = ti;
            }
        }
    }

    // u64 keys: (value_bits << 32) | (127 - idx). Non-negative floats -> bits
    // monotone; bigger low word = smaller idx = lax.top_k tie-break order.
    u64 key[4][K_];
    #pragma unroll
    for (int j = 0; j < 4; ++j)
        #pragma unroll
        for (int k = 0; k < K_; ++k)
            key[j][k] = ((u64)__float_as_uint(lv[j][k]) << 32)
                      | (unsigned int)(D_ - 1 - li[j][k]);

    // two bitonic merge stages across the depth quad (lanes ^1 then ^2);
    // all 4 lanes end up holding identical merged top-4 lists
    #pragma unroll
    for (int s = 1; s <= 2; s <<= 1) {
        #pragma unroll
        for (int j = 0; j < 4; ++j) {
            u64 b0 = __shfl_xor(key[j][0], s);
            u64 b1 = __shfl_xor(key[j][1], s);
            u64 b2 = __shfl_xor(key[j][2], s);
            u64 b3 = __shfl_xor(key[j][3], s);
            u64 m0 = umax64(key[j][0], b3);
            u64 m1 = umax64(key[j][1], b2);
            u64 m2 = umax64(key[j][2], b1);
            u64 m3 = umax64(key[j][3], b0);
            cswap_u64(m0, m2); cswap_u64(m1, m3);
            cswap_u64(m0, m1); cswap_u64(m2, m3);
            key[j][0] = m0; key[j][1] = m1; key[j][2] = m2; key[j][3] = m3;
        }
    }

    // each quad lane writes one k-slot: pred (raw value) + dep
    {
        const int k = quarter;
        float4 pv, dv;
        pv.x = __uint_as_float((unsigned int)(key[0][k] >> 32));
        pv.y = __uint_as_float((unsigned int)(key[1][k] >> 32));
        pv.z = __uint_as_float((unsigned int)(key[2][k] >> 32));
        pv.w = __uint_as_float((unsigned int)(key[3][k] >> 32));
        dv.x = (float)(int)(key[0][k] & 0xFFu) / 127.0f;
        dv.y = (float)(int)(key[1][k] & 0xFFu) / 127.0f;
        dv.z = (float)(int)(key[2][k] & 0xFFu) / 127.0f;
        dv.w = (float)(int)(key[3][k] & 0xFFu) / 127.0f;
        float4* base4 = (float4*)out;
        base4[(size_t)(bc * 2 * K_ + k) * GPB + grp]       = pv;  // pred ch
        base4[(size_t)((bc * 2 + 1) * K_ + k) * GPB + grp] = dv;  // dep ch
    }

    // min/max block reduction -> one atomic pair per block (block shares bc)
    float mx = fmaxf(fmaxf(__uint_as_float((unsigned int)(key[0][0] >> 32)),
                           __uint_as_float((unsigned int)(key[1][0] >> 32))),
                     fmaxf(__uint_as_float((unsigned int)(key[2][0] >> 32)),
                           __uint_as_float((unsigned int)(key[3][0] >> 32))));
    #pragma unroll
    for (int off = 32; off > 0; off >>= 1) {
        mn = fminf(mn, __shfl_xor(mn, off));
        mx = fmaxf(mx, __shfl_xor(mx, off));
    }
    __shared__ float smn[4], smx[4];
    const int wave = threadIdx.x >> 6;
    if ((threadIdx.x & 63) == 0) { smn[wave] = mn; smx[wave] = mx; }
    __syncthreads();
    if (threadIdx.x == 0) {
        float bmn = fminf(fminf(smn[0], smn[1]), fminf(smn[2], smn[3]));
        float bmx = fmaxf(fmaxf(smx[0], smx[1]), fmaxf(smx[2], smx[3]));
        atomicMin(&mm[2*bc],   __float_as_uint(bmn));
        atomicMax(&mm[2*bc+1], __float_as_uint(bmx));
    }
}

// Normalize pred channel in place: (v - mn) / ((mx - mn) + eps) * SCALE
__global__ __launch_bounds__(256) void norm_kernel(float* __restrict__ out,
                                                   const unsigned int* __restrict__ mm) {
    const int tid = blockIdx.x * 256 + threadIdx.x;   // float4 index over pred elems
    const int per_bc4 = K_ * HW_ / 4;                 // 65536
    const int bc = tid / per_bc4;
    if (bc >= NBC) return;
    const size_t n4 = (size_t)(tid - bc * per_bc4) + (size_t)(bc * 2) * per_bc4;
    const float mnv = __uint_as_float(mm[2*bc]);
    const float mxv = __uint_as_float(mm[2*bc+1]);
    const float den = (mxv - mnv) + EPS_;
    float4 v = ((float4*)out)[n4];
    v.x = (v.x - mnv) / den * SCALE_;
    v.y = (v.y - mnv) / den * SCALE_;
    v.z = (v.z - mnv) / den * SCALE_;
    v.w = (v.w - mnv) / den * SCALE_;
    ((float4*)out)[n4] = v;
}

extern "C" void kernel_launch(void* const* d_in, const int* in_sizes, int n_in,
                              void* d_out, int out_size, void* d_ws, size_t ws_size,
                              hipStream_t stream) {
    const float* x = (const float*)d_in[0];
    float* out = (float*)d_out;
    unsigned int* mm = (unsigned int*)d_ws;

    hipLaunchKernelGGL(init_mm_kernel, dim3(1), dim3(64), 0, stream, mm);

    const int threads1 = NBC * GPB * 4;               // 262144
    hipLaunchKernelGGL(topk_kernel, dim3(threads1 / 256), dim3(256), 0, stream,
                       x, out, mm);

    const int threads2 = NBC * K_ * HW_ / 4;          // 262144
    hipLaunchKernelGGL(norm_kernel, dim3(threads2 / 256), dim3(256), 0, stream,
                       out, mm);
}